// Round 3
// baseline (1201.601 us; speedup 1.0000x reference)
//
#include <hip/hip_runtime.h>
#include <hip/hip_bf16.h>
#include <float.h>
#include <math.h>

#define BB 8
#define NN 4096
#define CC 128
#define MROWS (BB * NN)   // 32768
#define EPSBN 1e-5f

#define QB 64             // queries per knn block
#define CT 64             // candidates per tile
#define NTILE (NN / CT)   // 64

typedef __attribute__((ext_vector_type(8))) short bf16x8;
typedef __attribute__((ext_vector_type(4))) float f32x4;

__device__ __forceinline__ ushort f2bf(float f) {
  uint u = __float_as_uint(f);
  u = u + 0x7fffu + ((u >> 16) & 1u);   // RNE
  return (ushort)(u >> 16);
}
__device__ __forceinline__ float bf2f(ushort h) {
  return __uint_as_float(((uint)h) << 16);
}

// ---------------------------------------------------------------------------
// Generic fp32 GEMM: out[M,128] = A[M,K] @ W[K,128] + bias
// ---------------------------------------------------------------------------
#define GBM 64
#define GBN 128
#define GBK 32

__global__ __launch_bounds__(256)
void gemm_bias_kernel(const float* __restrict__ A, const float* __restrict__ W,
                      const float* __restrict__ bias, float* __restrict__ out,
                      int M, int K) {
  __shared__ float As[GBK][GBM + 4];
  __shared__ float Ws[GBK][GBN + 4];
  int tid = threadIdx.x;
  int m0 = blockIdx.x * GBM;
  int ty = tid >> 4, tx = tid & 15;

  float acc[4][8];
#pragma unroll
  for (int i = 0; i < 4; ++i)
#pragma unroll
    for (int j = 0; j < 8; ++j) acc[i][j] = 0.f;

  for (int k0 = 0; k0 < K; k0 += GBK) {
    {
      int row = tid >> 2, ch = tid & 3;
      const float* ap = A + (long)(m0 + row) * K + k0 + ch * 8;
      float4 a0 = *(const float4*)ap;
      float4 a1 = *(const float4*)(ap + 4);
      float av2[8] = {a0.x, a0.y, a0.z, a0.w, a1.x, a1.y, a1.z, a1.w};
#pragma unroll
      for (int e = 0; e < 8; ++e) As[ch * 8 + e][row] = av2[e];
    }
#pragma unroll
    for (int c = 0; c < 4; ++c) {
      int lin = tid + 256 * c;
      int row = lin >> 5, c4 = (lin & 31) * 4;
      *(float4*)&Ws[row][c4] = *(const float4*)&W[(long)(k0 + row) * GBN + c4];
    }
    __syncthreads();
#pragma unroll
    for (int kk = 0; kk < GBK; ++kk) {
      float4 a4 = *(const float4*)&As[kk][ty * 4];
      float4 b0 = *(const float4*)&Ws[kk][tx * 8];
      float4 b1 = *(const float4*)&Ws[kk][tx * 8 + 4];
      float av[4] = {a4.x, a4.y, a4.z, a4.w};
      float bv[8] = {b0.x, b0.y, b0.z, b0.w, b1.x, b1.y, b1.z, b1.w};
#pragma unroll
      for (int i = 0; i < 4; ++i)
#pragma unroll
        for (int j = 0; j < 8; ++j)
          acc[i][j] = fmaf(av[i], bv[j], acc[i][j]);
    }
    __syncthreads();
  }
  float4 bi0 = *(const float4*)&bias[tx * 8];
  float4 bi1 = *(const float4*)&bias[tx * 8 + 4];
#pragma unroll
  for (int i = 0; i < 4; ++i) {
    long r = (long)(m0 + ty * 4 + i);
    float4 o0 = {acc[i][0] + bi0.x, acc[i][1] + bi0.y, acc[i][2] + bi0.z, acc[i][3] + bi0.w};
    float4 o1 = {acc[i][4] + bi1.x, acc[i][5] + bi1.y, acc[i][6] + bi1.z, acc[i][7] + bi1.w};
    *(float4*)&out[r * GBN + tx * 8] = o0;
    *(float4*)&out[r * GBN + tx * 8 + 4] = o1;
  }
}

// ---------------------------------------------------------------------------
// Column stats: sum/sumsq per channel over 32768 rows (atomics into zeroed ws)
// ---------------------------------------------------------------------------
__global__ __launch_bounds__(256)
void colstats_kernel(const float* __restrict__ X, float* __restrict__ sum,
                     float* __restrict__ sumsq) {
  __shared__ float s1[256], s2[256];
  int tid = threadIdx.x;
  int c = tid & 127, rg = tid >> 7;
  int r0 = blockIdx.x * 256;
  float s = 0.f, ss = 0.f;
  for (int i = 0; i < 128; ++i) {
    float v = X[(long)(r0 + rg + i * 2) * CC + c];
    s += v; ss += v * v;
  }
  s1[tid] = s; s2[tid] = ss;
  __syncthreads();
  if (rg == 0) {
    s += s1[tid + 128]; ss += s2[tid + 128];
    atomicAdd(&sum[c], s);
    atomicAdd(&sumsq[c], ss);
  }
}

// ---------------------------------------------------------------------------
// BN apply (stage 1) + h into cat[:, :128] + bf16 hi/lo split + row sq-norms
// ---------------------------------------------------------------------------
__global__ __launch_bounds__(256)
void bn_split_kernel(const float* __restrict__ X, const float* __restrict__ sum,
                     const float* __restrict__ sumsq, const float* __restrict__ g,
                     const float* __restrict__ be, float* __restrict__ cat,
                     ushort* __restrict__ hHi, ushort* __restrict__ hLo,
                     float* __restrict__ sqv) {
  int gid = blockIdx.x * 256 + threadIdx.x;   // quad id
  int row = gid >> 5;
  int c4 = (gid & 31) * 4;
  const float inv = 1.0f / (float)MROWS;
  float4 x  = *(const float4*)&X[(long)row * CC + c4];
  float4 sm = *(const float4*)&sum[c4];
  float4 sq = *(const float4*)&sumsq[c4];
  float4 gv = *(const float4*)&g[c4];
  float4 bv = *(const float4*)&be[c4];
  float xv[4] = {x.x, x.y, x.z, x.w};
  float smv[4] = {sm.x, sm.y, sm.z, sm.w};
  float sqv2[4] = {sq.x, sq.y, sq.z, sq.w};
  float ga[4] = {gv.x, gv.y, gv.z, gv.w};
  float ba[4] = {bv.x, bv.y, bv.z, bv.w};
  float h[4];
  ushort hi[4], lo[4];
#pragma unroll
  for (int e = 0; e < 4; ++e) {
    float m = smv[e] * inv;
    float v = sqv2[e] * inv - m * m;
    float sc = ga[e] * rsqrtf(v + EPSBN);
    h[e] = (xv[e] - m) * sc + ba[e];
    hi[e] = f2bf(h[e]);
    lo[e] = f2bf(h[e] - bf2f(hi[e]));
  }
  float4 hv = {h[0], h[1], h[2], h[3]};
  *(float4*)&cat[(long)row * 256 + c4] = hv;
  ushort4 h4 = {hi[0], hi[1], hi[2], hi[3]};
  ushort4 l4 = {lo[0], lo[1], lo[2], lo[3]};
  *(ushort4*)&hHi[(long)row * CC + c4] = h4;
  *(ushort4*)&hLo[(long)row * CC + c4] = l4;
  // fused row squared-norm: 32 threads per row (within one 32-lane half)
  float s = h[0] * h[0] + h[1] * h[1] + h[2] * h[2] + h[3] * h[3];
#pragma unroll
  for (int off = 16; off >= 1; off >>= 1) s += __shfl_xor(s, off, 64);
  if ((threadIdx.x & 31) == 0) sqv[row] = s;
}

// ---------------------------------------------------------------------------
// top-9 sorted insert (fully unrolled predicated network, stays in registers)
// ---------------------------------------------------------------------------
__device__ __forceinline__ void insert9(float (&dk)[9], int (&ik)[9], float s, int idx) {
  bool sh[9];
#pragma unroll
  for (int k = 0; k < 9; ++k) sh[k] = s < dk[k];
#pragma unroll
  for (int k = 8; k >= 1; --k) {
    if (sh[k]) {
      bool up = sh[k - 1];
      dk[k] = up ? dk[k - 1] : s;
      ik[k] = up ? ik[k - 1] : idx;
    }
  }
  if (sh[0]) { dk[0] = s; ik[0] = idx; }
}

__device__ __forceinline__ void insert9_lex(float (&dk)[9], int (&ik)[9], float pd, int pi) {
  bool ins = (pd < dk[8]) || (pd == dk[8] && pi < ik[8]);
  if (ins) {
    bool sh[9];
#pragma unroll
    for (int t = 0; t < 9; ++t)
      sh[t] = (pd < dk[t]) || (pd == dk[t] && pi < ik[t]);
#pragma unroll
    for (int t = 8; t >= 1; --t) {
      if (sh[t]) {
        bool up = sh[t - 1];
        dk[t] = up ? dk[t - 1] : pd;
        ik[t] = up ? ik[t - 1] : pi;
      }
    }
    if (sh[0]) { dk[0] = pd; ik[0] = pi; }
  }
}

// ---------------------------------------------------------------------------
// Fused: pairwise dist (split-bf16, 3 MFMA passes) + top-9 + max-relative agg
// Block = 64 queries (512 blocks, blockIdx&7 = batch for XCD-L2 locality).
// Wave w owns candidates w*16..w*16+15 of each 64-candidate tile; all 64
// query fragments (hi+lo) persistent in registers. 2 blocks/CU.
// LDS: cs tiles 32 KB (XOR-swizzled, conflict-free) + scoreT 17 KB + sqs.
// ---------------------------------------------------------------------------
#define SCST 68   // scoreT stride (floats): 4*(l15+quad) mod 32 -> conflict-free

__global__ __launch_bounds__(256, 2)
void knn_agg_kernel(const ushort* __restrict__ hHi, const ushort* __restrict__ hLo,
                    const float* __restrict__ sqv, const float* __restrict__ cat,
                    float* __restrict__ catw) {
  __shared__ ushort csHi[CT * 128];       // 16 KB, swizzled chunks
  __shared__ ushort csLo[CT * 128];       // 16 KB
  __shared__ float  sqs[CT];
  __shared__ float  scoreT[CT * SCST];    // [cand][query], 17.4 KB

  int tid = threadIdx.x;
  int wave = tid >> 6, lane = tid & 63;
  int l15 = lane & 15, quad = lane >> 4;
  int b = blockIdx.x & 7, qt = blockIdx.x >> 3;
  long brow = (long)b * NN;
  long rowbase = brow + (long)qt * QB;

  // persistent A-fragments: all 64 queries, hi+lo (128 VGPRs)
  bf16x8 aHi[4][4], aLo[4][4];
#pragma unroll
  for (int rg = 0; rg < 4; ++rg) {
    long gq = rowbase + rg * 16 + l15;
    const ushort* ph = hHi + gq * CC + quad * 8;
    const ushort* pl = hLo + gq * CC + quad * 8;
#pragma unroll
    for (int ks = 0; ks < 4; ++ks) {
      aHi[rg][ks] = *(const bf16x8*)(ph + ks * 32);
      aLo[rg][ks] = *(const bf16x8*)(pl + ks * 32);
    }
  }

  float dk[9]; int ik[9];
#pragma unroll
  for (int k = 0; k < 9; ++k) { dk[k] = FLT_MAX; ik[k] = 0x7FFFFFFF; }
  int q = tid & 63, quarter = tid >> 6;

  // staging registers (inline, no lambdas -> stays in VGPRs)
  uint4 pH[4], pL[4];
  float psq = 0.f;

  // ---- prologue: tile 0 -> LDS, tile 1 -> regs ----
#pragma unroll
  for (int it = 0; it < 4; ++it) {
    int chunk = tid + it * 256;
    int row = chunk >> 4, c = chunk & 15;
    long grow = brow + row;
    pH[it] = *(const uint4*)(hHi + grow * CC + c * 8);
    pL[it] = *(const uint4*)(hLo + grow * CC + c * 8);
  }
#pragma unroll
  for (int it = 0; it < 4; ++it) {
    int chunk = tid + it * 256;
    int row = chunk >> 4, c = chunk & 15;
    int p = c ^ (row & 7);
    *(uint4*)&csHi[row * 128 + p * 8] = pH[it];
    *(uint4*)&csLo[row * 128 + p * 8] = pL[it];
  }
  if (tid < CT) sqs[tid] = sqv[brow + tid];
#pragma unroll
  for (int it = 0; it < 4; ++it) {
    int chunk = tid + it * 256;
    int row = chunk >> 4, c = chunk & 15;
    long grow = brow + CT + row;
    pH[it] = *(const uint4*)(hHi + grow * CC + c * 8);
    pL[it] = *(const uint4*)(hLo + grow * CC + c * 8);
  }
  if (tid < CT) psq = sqv[brow + CT + tid];
  __syncthreads();

#pragma unroll 1
  for (int ct = 0; ct < NTILE; ++ct) {
    // ---- MFMA: this wave's 16 candidates x all 64 queries ----
    bf16x8 bHi[4], bLo[4];
    int crow = wave * 16 + l15;
#pragma unroll
    for (int ks = 0; ks < 4; ++ks) {
      int p = (ks * 4 + quad) ^ (l15 & 7);
      bHi[ks] = *(const bf16x8*)&csHi[crow * 128 + p * 8];
      bLo[ks] = *(const bf16x8*)&csLo[crow * 128 + p * 8];
    }
    float sqc = sqs[crow];
#pragma unroll 1
    for (int rg = 0; rg < 4; ++rg) {
      f32x4 ac[4];
#pragma unroll
      for (int ks = 0; ks < 4; ++ks) { ac[ks].x = 0.f; ac[ks].y = 0.f; ac[ks].z = 0.f; ac[ks].w = 0.f; }
#pragma unroll
      for (int ks = 0; ks < 4; ++ks) {
        ac[ks] = __builtin_amdgcn_mfma_f32_16x16x32_bf16(aHi[rg][ks], bHi[ks], ac[ks], 0, 0, 0);
        ac[ks] = __builtin_amdgcn_mfma_f32_16x16x32_bf16(aHi[rg][ks], bLo[ks], ac[ks], 0, 0, 0);
        ac[ks] = __builtin_amdgcn_mfma_f32_16x16x32_bf16(aLo[rg][ks], bHi[ks], ac[ks], 0, 0, 0);
      }
      f32x4 acc = (ac[0] + ac[1]) + (ac[2] + ac[3]);
      // lane holds candidate crow, queries rg*16 + quad*4 + 0..3 -> b128 write
      float4 o = {fmaf(-2.f, acc.x, sqc), fmaf(-2.f, acc.y, sqc),
                  fmaf(-2.f, acc.z, sqc), fmaf(-2.f, acc.w, sqc)};
      *(float4*)&scoreT[crow * SCST + rg * 16 + quad * 4] = o;
    }
    __syncthreads();   // scores ready; cs(ct) consumed

    // ---- scan phase: stage tile ct+1 -> LDS, prefetch ct+2 -> regs ----
#pragma unroll
    for (int it = 0; it < 4; ++it) {
      int chunk = tid + it * 256;
      int row = chunk >> 4, c = chunk & 15;
      int p = c ^ (row & 7);
      *(uint4*)&csHi[row * 128 + p * 8] = pH[it];
      *(uint4*)&csLo[row * 128 + p * 8] = pL[it];
    }
    if (tid < CT) sqs[tid] = psq;
    int nt = (ct + 2) & (NTILE - 1);
#pragma unroll
    for (int it = 0; it < 4; ++it) {
      int chunk = tid + it * 256;
      int row = chunk >> 4, c = chunk & 15;
      long grow = brow + (long)nt * CT + row;
      pH[it] = *(const uint4*)(hHi + grow * CC + c * 8);
      pL[it] = *(const uint4*)(hLo + grow * CC + c * 8);
    }
    if (tid < CT) psq = sqv[brow + (long)nt * CT + tid];

    // thread (q, quarter) scans candidates quarter*16..+15 of this tile
    int gbase = ct * CT + quarter * 16;
    const float* scol = &scoreT[(quarter * 16) * SCST + q];
    float thr = dk[8];
#pragma unroll
    for (int jj = 0; jj < 16; jj += 4) {
      float s0 = scol[(jj + 0) * SCST];
      float s1 = scol[(jj + 1) * SCST];
      float s2 = scol[(jj + 2) * SCST];
      float s3 = scol[(jj + 3) * SCST];
      float mn = fminf(fminf(s0, s1), fminf(s2, s3));
      if (mn < thr) {
        if (s0 < thr) { insert9(dk, ik, s0, gbase + jj + 0); thr = dk[8]; }
        if (s1 < thr) { insert9(dk, ik, s1, gbase + jj + 1); thr = dk[8]; }
        if (s2 < thr) { insert9(dk, ik, s2, gbase + jj + 2); thr = dk[8]; }
        if (s3 < thr) { insert9(dk, ik, s3, gbase + jj + 3); thr = dk[8]; }
      }
    }
    __syncthreads();   // cs(ct+1)/sqs staged; scoreT consumed
  }

  // ---- merge 4 quarter top-9s per query (lexicographic tie-break) ----
  float* mD = scoreT;                        // 3*64*9 = 1728 floats
  int*   mI = (int*)(scoreT + 1728);         // 1728 ints
  int*   fI = (int*)(scoreT + 3456);         // 576 ints (fits: 4352 total)
  if (quarter > 0) {
    int base = (quarter - 1) * 576 + q * 9;
#pragma unroll
    for (int k = 0; k < 9; ++k) { mD[base + k] = dk[k]; mI[base + k] = ik[k]; }
  }
  __syncthreads();
  if (quarter == 0) {
#pragma unroll 1
    for (int qq = 0; qq < 3; ++qq) {
      int base = qq * 576 + q * 9;
#pragma unroll 1
      for (int k = 0; k < 9; ++k)
        insert9_lex(dk, ik, mD[base + k], mI[base + k]);
    }
#pragma unroll
    for (int k = 0; k < 9; ++k) fI[q * 9 + k] = ik[k];
  }
  __syncthreads();

  // ---- aggregation: agg[q,c] = max_k h[nbr_k][c] - h[q][c] -> cat[:,128:256]
  int nb[9];
#pragma unroll
  for (int k = 0; k < 9; ++k) nb[k] = fI[q * 9 + k];
  long qrow = rowbase + q;
  const float4* cat4 = (const float4*)cat;
  float4* catw4 = (float4*)catw;
#pragma unroll 1
  for (int c4 = 0; c4 < 8; ++c4) {
    int cc = quarter * 8 + c4;
    float4 hq = cat4[qrow * 64 + cc];
    float4 mx = {-FLT_MAX, -FLT_MAX, -FLT_MAX, -FLT_MAX};
#pragma unroll
    for (int k = 0; k < 9; ++k) {
      float4 v = cat4[(brow + nb[k]) * 64 + cc];
      mx.x = fmaxf(mx.x, v.x - hq.x);
      mx.y = fmaxf(mx.y, v.y - hq.y);
      mx.z = fmaxf(mx.z, v.z - hq.z);
      mx.w = fmaxf(mx.w, v.w - hq.w);
    }
    catw4[qrow * 64 + 32 + cc] = mx;
  }
}

// ---------------------------------------------------------------------------
// BN + exact GELU (stage 2)
// ---------------------------------------------------------------------------
__global__ __launch_bounds__(256)
void bn_gelu_kernel(const float* __restrict__ X, const float* __restrict__ sum,
                    const float* __restrict__ sumsq, const float* __restrict__ g,
                    const float* __restrict__ be, float* __restrict__ out) {
  int gid = blockIdx.x * 256 + threadIdx.x;
  int row = gid >> 5;
  int c4 = (gid & 31) * 4;
  const float inv = 1.0f / (float)MROWS;
  float4 x  = *(const float4*)&X[(long)row * CC + c4];
  float4 sm = *(const float4*)&sum[c4];
  float4 sq = *(const float4*)&sumsq[c4];
  float4 gv = *(const float4*)&g[c4];
  float4 bv = *(const float4*)&be[c4];
  float xv[4] = {x.x, x.y, x.z, x.w};
  float smv[4] = {sm.x, sm.y, sm.z, sm.w};
  float sqv2[4] = {sq.x, sq.y, sq.z, sq.w};
  float ga[4] = {gv.x, gv.y, gv.z, gv.w};
  float ba[4] = {bv.x, bv.y, bv.z, bv.w};
  float o[4];
#pragma unroll
  for (int e = 0; e < 4; ++e) {
    float m = smv[e] * inv;
    float v = sqv2[e] * inv - m * m;
    float sc = ga[e] * rsqrtf(v + EPSBN);
    float h = (xv[e] - m) * sc + ba[e];
    o[e] = 0.5f * h * (1.0f + erff(h * 0.70710678118654752f));
  }
  float4 ov = {o[0], o[1], o[2], o[3]};
  *(float4*)&out[(long)row * CC + c4] = ov;
}

// ---------------------------------------------------------------------------
// BN + residual (stage 3) -> d_out
// ---------------------------------------------------------------------------
__global__ __launch_bounds__(256)
void bn_res_kernel(const float* __restrict__ X, const float* __restrict__ sum,
                   const float* __restrict__ sumsq, const float* __restrict__ g,
                   const float* __restrict__ be, const float* __restrict__ xres,
                   float* __restrict__ out) {
  int gid = blockIdx.x * 256 + threadIdx.x;
  int row = gid >> 5;
  int c4 = (gid & 31) * 4;
  const float inv = 1.0f / (float)MROWS;
  float4 x  = *(const float4*)&X[(long)row * CC + c4];
  float4 rr = *(const float4*)&xres[(long)row * CC + c4];
  float4 sm = *(const float4*)&sum[c4];
  float4 sq = *(const float4*)&sumsq[c4];
  float4 gv = *(const float4*)&g[c4];
  float4 bv = *(const float4*)&be[c4];
  float xv[4] = {x.x, x.y, x.z, x.w};
  float rv[4] = {rr.x, rr.y, rr.z, rr.w};
  float smv[4] = {sm.x, sm.y, sm.z, sm.w};
  float sqv2[4] = {sq.x, sq.y, sq.z, sq.w};
  float ga[4] = {gv.x, gv.y, gv.z, gv.w};
  float ba[4] = {bv.x, bv.y, bv.z, bv.w};
  float o[4];
#pragma unroll
  for (int e = 0; e < 4; ++e) {
    float m = smv[e] * inv;
    float v = sqv2[e] * inv - m * m;
    float sc = ga[e] * rsqrtf(v + EPSBN);
    o[e] = (xv[e] - m) * sc + ba[e] + rv[e];
  }
  float4 ov = {o[0], o[1], o[2], o[3]};
  *(float4*)&out[(long)row * CC + c4] = ov;
}

// ---------------------------------------------------------------------------
extern "C" void kernel_launch(void* const* d_in, const int* in_sizes, int n_in,
                              void* d_out, int out_size, void* d_ws, size_t ws_size,
                              hipStream_t stream) {
  const float* x   = (const float*)d_in[0];
  const float* W1  = (const float*)d_in[1];
  const float* b1  = (const float*)d_in[2];
  const float* g1  = (const float*)d_in[3];
  const float* be1 = (const float*)d_in[4];
  const float* Wg  = (const float*)d_in[5];
  const float* bg  = (const float*)d_in[6];
  const float* ggp = (const float*)d_in[7];
  const float* beg = (const float*)d_in[8];
  const float* W2  = (const float*)d_in[9];
  const float* b2  = (const float*)d_in[10];
  const float* g2  = (const float*)d_in[11];
  const float* be2 = (const float*)d_in[12];
  float* out = (float*)d_out;

  char* p = (char*)d_ws;
  auto alloc = [&](size_t bytes) {
    char* r = p;
    p += (bytes + 255) & ~(size_t)255;
    return r;
  };
  float*  bufA = (float*)alloc((size_t)MROWS * CC * 4);    // h_pre / hg_pre / out_pre
  float*  cat  = (float*)alloc((size_t)MROWS * 256 * 4);   // [h | agg]
  ushort* hHi  = (ushort*)alloc((size_t)MROWS * CC * 2);
  ushort* hLo  = (ushort*)alloc((size_t)MROWS * CC * 2);
  float*  sqv  = (float*)alloc((size_t)MROWS * 4);
  float*  hg   = (float*)alloc((size_t)MROWS * CC * 4);
  float*  stats = (float*)alloc(6 * CC * 4);
  float* sum1 = stats,       *ss1 = stats + 128;
  float* sum2 = stats + 256, *ss2 = stats + 384;
  float* sum3 = stats + 512, *ss3 = stats + 640;

  hipMemsetAsync(stats, 0, 6 * CC * 4, stream);

  // fc1 + BN -> h (fp32 in cat[:, :128]) + bf16 hi/lo split + row norms
  gemm_bias_kernel<<<MROWS / GBM, 256, 0, stream>>>(x, W1, b1, bufA, MROWS, CC);
  colstats_kernel<<<128, 256, 0, stream>>>(bufA, sum1, ss1);
  bn_split_kernel<<<MROWS / 8, 256, 0, stream>>>(bufA, sum1, ss1, g1, be1, cat, hHi, hLo, sqv);

  // KNN (split-bf16 MFMA distances, 3-pass) + top-9 + max-rel agg -> cat[:,128:]
  knn_agg_kernel<<<512, 256, 0, stream>>>(hHi, hLo, sqv, cat, cat);

  // graph MLP: cat @ Wg + BN + GELU
  gemm_bias_kernel<<<MROWS / GBM, 256, 0, stream>>>(cat, Wg, bg, bufA, MROWS, 2 * CC);
  colstats_kernel<<<128, 256, 0, stream>>>(bufA, sum2, ss2);
  bn_gelu_kernel<<<MROWS / 8, 256, 0, stream>>>(bufA, sum2, ss2, ggp, beg, hg);

  // fc2 + BN + residual
  gemm_bias_kernel<<<MROWS / GBM, 256, 0, stream>>>(hg, W2, b2, bufA, MROWS, CC);
  colstats_kernel<<<128, 256, 0, stream>>>(bufA, sum3, ss3);
  bn_res_kernel<<<MROWS / 8, 256, 0, stream>>>(bufA, sum3, ss3, g2, be2, x, out);
}

// Round 4
// 573.010 us; speedup vs baseline: 2.0970x; 2.0970x over previous
//
#include <hip/hip_runtime.h>
#include <hip/hip_bf16.h>
#include <float.h>
#include <math.h>

#define BB 8
#define NN 4096
#define CC 128
#define MROWS (BB * NN)   // 32768
#define EPSBN 1e-5f

#define QB 64             // queries per knn block
#define CT 64             // candidates per tile
#define NTILE (NN / CT)   // 64

typedef __attribute__((ext_vector_type(8))) short bf16x8;
typedef __attribute__((ext_vector_type(4))) float f32x4;

__device__ __forceinline__ ushort f2bf(float f) {
  uint u = __float_as_uint(f);
  u = u + 0x7fffu + ((u >> 16) & 1u);   // RNE
  return (ushort)(u >> 16);
}
__device__ __forceinline__ float bf2f(ushort h) {
  return __uint_as_float(((uint)h) << 16);
}

// ---------------------------------------------------------------------------
// Generic fp32 GEMM: out[M,128] = A[M,K] @ W[K,128] + bias
// ---------------------------------------------------------------------------
#define GBM 64
#define GBN 128
#define GBK 32

__global__ __launch_bounds__(256)
void gemm_bias_kernel(const float* __restrict__ A, const float* __restrict__ W,
                      const float* __restrict__ bias, float* __restrict__ out,
                      int M, int K) {
  __shared__ float As[GBK][GBM + 4];
  __shared__ float Ws[GBK][GBN + 4];
  int tid = threadIdx.x;
  int m0 = blockIdx.x * GBM;
  int ty = tid >> 4, tx = tid & 15;

  float acc[4][8];
#pragma unroll
  for (int i = 0; i < 4; ++i)
#pragma unroll
    for (int j = 0; j < 8; ++j) acc[i][j] = 0.f;

  for (int k0 = 0; k0 < K; k0 += GBK) {
    {
      int row = tid >> 2, ch = tid & 3;
      const float* ap = A + (long)(m0 + row) * K + k0 + ch * 8;
      float4 a0 = *(const float4*)ap;
      float4 a1 = *(const float4*)(ap + 4);
      float av2[8] = {a0.x, a0.y, a0.z, a0.w, a1.x, a1.y, a1.z, a1.w};
#pragma unroll
      for (int e = 0; e < 8; ++e) As[ch * 8 + e][row] = av2[e];
    }
#pragma unroll
    for (int c = 0; c < 4; ++c) {
      int lin = tid + 256 * c;
      int row = lin >> 5, c4 = (lin & 31) * 4;
      *(float4*)&Ws[row][c4] = *(const float4*)&W[(long)(k0 + row) * GBN + c4];
    }
    __syncthreads();
#pragma unroll
    for (int kk = 0; kk < GBK; ++kk) {
      float4 a4 = *(const float4*)&As[kk][ty * 4];
      float4 b0 = *(const float4*)&Ws[kk][tx * 8];
      float4 b1 = *(const float4*)&Ws[kk][tx * 8 + 4];
      float av[4] = {a4.x, a4.y, a4.z, a4.w};
      float bv[8] = {b0.x, b0.y, b0.z, b0.w, b1.x, b1.y, b1.z, b1.w};
#pragma unroll
      for (int i = 0; i < 4; ++i)
#pragma unroll
        for (int j = 0; j < 8; ++j)
          acc[i][j] = fmaf(av[i], bv[j], acc[i][j]);
    }
    __syncthreads();
  }
  float4 bi0 = *(const float4*)&bias[tx * 8];
  float4 bi1 = *(const float4*)&bias[tx * 8 + 4];
#pragma unroll
  for (int i = 0; i < 4; ++i) {
    long r = (long)(m0 + ty * 4 + i);
    float4 o0 = {acc[i][0] + bi0.x, acc[i][1] + bi0.y, acc[i][2] + bi0.z, acc[i][3] + bi0.w};
    float4 o1 = {acc[i][4] + bi1.x, acc[i][5] + bi1.y, acc[i][6] + bi1.z, acc[i][7] + bi1.w};
    *(float4*)&out[r * GBN + tx * 8] = o0;
    *(float4*)&out[r * GBN + tx * 8 + 4] = o1;
  }
}

// ---------------------------------------------------------------------------
// Column stats: sum/sumsq per channel over 32768 rows (atomics into zeroed ws)
// ---------------------------------------------------------------------------
__global__ __launch_bounds__(256)
void colstats_kernel(const float* __restrict__ X, float* __restrict__ sum,
                     float* __restrict__ sumsq) {
  __shared__ float s1[256], s2[256];
  int tid = threadIdx.x;
  int c = tid & 127, rg = tid >> 7;
  int r0 = blockIdx.x * 256;
  float s = 0.f, ss = 0.f;
  for (int i = 0; i < 128; ++i) {
    float v = X[(long)(r0 + rg + i * 2) * CC + c];
    s += v; ss += v * v;
  }
  s1[tid] = s; s2[tid] = ss;
  __syncthreads();
  if (rg == 0) {
    s += s1[tid + 128]; ss += s2[tid + 128];
    atomicAdd(&sum[c], s);
    atomicAdd(&sumsq[c], ss);
  }
}

// ---------------------------------------------------------------------------
// BN apply (stage 1) + h into cat[:, :128] + bf16 hi/lo split + row sq-norms
// ---------------------------------------------------------------------------
__global__ __launch_bounds__(256)
void bn_split_kernel(const float* __restrict__ X, const float* __restrict__ sum,
                     const float* __restrict__ sumsq, const float* __restrict__ g,
                     const float* __restrict__ be, float* __restrict__ cat,
                     ushort* __restrict__ hHi, ushort* __restrict__ hLo,
                     float* __restrict__ sqv) {
  int gid = blockIdx.x * 256 + threadIdx.x;   // quad id
  int row = gid >> 5;
  int c4 = (gid & 31) * 4;
  const float inv = 1.0f / (float)MROWS;
  float4 x  = *(const float4*)&X[(long)row * CC + c4];
  float4 sm = *(const float4*)&sum[c4];
  float4 sq = *(const float4*)&sumsq[c4];
  float4 gv = *(const float4*)&g[c4];
  float4 bv = *(const float4*)&be[c4];
  float xv[4] = {x.x, x.y, x.z, x.w};
  float smv[4] = {sm.x, sm.y, sm.z, sm.w};
  float sqv2[4] = {sq.x, sq.y, sq.z, sq.w};
  float ga[4] = {gv.x, gv.y, gv.z, gv.w};
  float ba[4] = {bv.x, bv.y, bv.z, bv.w};
  float h[4];
  ushort hi[4], lo[4];
#pragma unroll
  for (int e = 0; e < 4; ++e) {
    float m = smv[e] * inv;
    float v = sqv2[e] * inv - m * m;
    float sc = ga[e] * rsqrtf(v + EPSBN);
    h[e] = (xv[e] - m) * sc + ba[e];
    hi[e] = f2bf(h[e]);
    lo[e] = f2bf(h[e] - bf2f(hi[e]));
  }
  float4 hv = {h[0], h[1], h[2], h[3]};
  *(float4*)&cat[(long)row * 256 + c4] = hv;
  ushort4 h4 = {hi[0], hi[1], hi[2], hi[3]};
  ushort4 l4 = {lo[0], lo[1], lo[2], lo[3]};
  *(ushort4*)&hHi[(long)row * CC + c4] = h4;
  *(ushort4*)&hLo[(long)row * CC + c4] = l4;
  // fused row squared-norm: 32 threads per row (within one 32-lane half)
  float s = h[0] * h[0] + h[1] * h[1] + h[2] * h[2] + h[3] * h[3];
#pragma unroll
  for (int off = 16; off >= 1; off >>= 1) s += __shfl_xor(s, off, 64);
  if ((threadIdx.x & 31) == 0) sqv[row] = s;
}

// ---------------------------------------------------------------------------
// top-9 sorted insert (fully unrolled predicated network, stays in registers)
// ---------------------------------------------------------------------------
__device__ __forceinline__ void insert9(float (&dk)[9], int (&ik)[9], float s, int idx) {
  bool sh[9];
#pragma unroll
  for (int k = 0; k < 9; ++k) sh[k] = s < dk[k];
#pragma unroll
  for (int k = 8; k >= 1; --k) {
    if (sh[k]) {
      bool up = sh[k - 1];
      dk[k] = up ? dk[k - 1] : s;
      ik[k] = up ? ik[k - 1] : idx;
    }
  }
  if (sh[0]) { dk[0] = s; ik[0] = idx; }
}

__device__ __forceinline__ void insert9_lex(float (&dk)[9], int (&ik)[9], float pd, int pi) {
  bool ins = (pd < dk[8]) || (pd == dk[8] && pi < ik[8]);
  if (ins) {
    bool sh[9];
#pragma unroll
    for (int t = 0; t < 9; ++t)
      sh[t] = (pd < dk[t]) || (pd == dk[t] && pi < ik[t]);
#pragma unroll
    for (int t = 8; t >= 1; --t) {
      if (sh[t]) {
        bool up = sh[t - 1];
        dk[t] = up ? dk[t - 1] : pd;
        ik[t] = up ? ik[t - 1] : pi;
      }
    }
    if (sh[0]) { dk[0] = pd; ik[0] = pi; }
  }
}

// ---------------------------------------------------------------------------
// Fused: pairwise dist (split-bf16, 3 MFMA passes) + top-9 + max-relative agg
// Block = 64 queries (512 blocks, blockIdx&7 = batch for XCD-L2 locality).
// Wave w owns candidates w*16..w*16+15 of each 64-candidate tile; all 64
// query fragments (hi+lo) persistent in registers (fully static indexing —
// any dynamic index here sends 128 VGPRs to scratch, the R2/R3 failure).
// ---------------------------------------------------------------------------
#define SCST 68   // scoreT stride (floats)

__global__ __launch_bounds__(256, 2)
void knn_agg_kernel(const ushort* __restrict__ hHi, const ushort* __restrict__ hLo,
                    const float* __restrict__ sqv, const float* __restrict__ cat,
                    float* __restrict__ catw) {
  __shared__ ushort csHi[CT * 128];       // 16 KB, swizzled chunks
  __shared__ ushort csLo[CT * 128];       // 16 KB
  __shared__ float  sqs[CT];
  __shared__ float  scoreT[CT * SCST];    // [cand][query], 17.4 KB

  int tid = threadIdx.x;
  int wave = tid >> 6, lane = tid & 63;
  int l15 = lane & 15, quad = lane >> 4;
  int b = blockIdx.x & 7, qt = blockIdx.x >> 3;
  long brow = (long)b * NN;
  long rowbase = brow + (long)qt * QB;

  // persistent A-fragments: all 64 queries, hi+lo (128 VGPRs)
  bf16x8 aHi[4][4], aLo[4][4];
#pragma unroll
  for (int rg = 0; rg < 4; ++rg) {
    long gq = rowbase + rg * 16 + l15;
    const ushort* ph = hHi + gq * CC + quad * 8;
    const ushort* pl = hLo + gq * CC + quad * 8;
#pragma unroll
    for (int ks = 0; ks < 4; ++ks) {
      aHi[rg][ks] = *(const bf16x8*)(ph + ks * 32);
      aLo[rg][ks] = *(const bf16x8*)(pl + ks * 32);
    }
  }

  float dk[9]; int ik[9];
#pragma unroll
  for (int k = 0; k < 9; ++k) { dk[k] = FLT_MAX; ik[k] = 0x7FFFFFFF; }
  int q = tid & 63, quarter = tid >> 6;

  // staging prefetch registers
  uint4 pH[4], pL[4];
  float psq = 0.f;

  // ---- prologue: tile 0 -> LDS, tile 1 -> regs ----
#pragma unroll
  for (int it = 0; it < 4; ++it) {
    int chunk = tid + it * 256;
    int row = chunk >> 4, c = chunk & 15;
    long grow = brow + row;
    pH[it] = *(const uint4*)(hHi + grow * CC + c * 8);
    pL[it] = *(const uint4*)(hLo + grow * CC + c * 8);
  }
#pragma unroll
  for (int it = 0; it < 4; ++it) {
    int chunk = tid + it * 256;
    int row = chunk >> 4, c = chunk & 15;
    int p = c ^ (row & 7);
    *(uint4*)&csHi[row * 128 + p * 8] = pH[it];
    *(uint4*)&csLo[row * 128 + p * 8] = pL[it];
  }
  if (tid < CT) sqs[tid] = sqv[brow + tid];
#pragma unroll
  for (int it = 0; it < 4; ++it) {
    int chunk = tid + it * 256;
    int row = chunk >> 4, c = chunk & 15;
    long grow = brow + CT + row;
    pH[it] = *(const uint4*)(hHi + grow * CC + c * 8);
    pL[it] = *(const uint4*)(hLo + grow * CC + c * 8);
  }
  if (tid < CT) psq = sqv[brow + CT + tid];
  __syncthreads();

#pragma unroll 1
  for (int ct = 0; ct < NTILE; ++ct) {
    // ---- MFMA: this wave's 16 candidates x all 64 queries ----
    // ks outer (one bHi/bLo pair live), rg inner (4 independent acc chains).
    int crow = wave * 16 + l15;
    float sqc = sqs[crow];
    f32x4 ac[4];
#pragma unroll
    for (int rg = 0; rg < 4; ++rg) { ac[rg].x = 0.f; ac[rg].y = 0.f; ac[rg].z = 0.f; ac[rg].w = 0.f; }
#pragma unroll
    for (int ks = 0; ks < 4; ++ks) {
      int p = (ks * 4 + quad) ^ (l15 & 7);
      bf16x8 bHi = *(const bf16x8*)&csHi[crow * 128 + p * 8];
      bf16x8 bLo = *(const bf16x8*)&csLo[crow * 128 + p * 8];
#pragma unroll
      for (int rg = 0; rg < 4; ++rg) {
        ac[rg] = __builtin_amdgcn_mfma_f32_16x16x32_bf16(aHi[rg][ks], bHi, ac[rg], 0, 0, 0);
        ac[rg] = __builtin_amdgcn_mfma_f32_16x16x32_bf16(aHi[rg][ks], bLo, ac[rg], 0, 0, 0);
        ac[rg] = __builtin_amdgcn_mfma_f32_16x16x32_bf16(aLo[rg][ks], bHi, ac[rg], 0, 0, 0);
      }
    }
#pragma unroll
    for (int rg = 0; rg < 4; ++rg) {
      // lane holds cand crow, queries rg*16 + quad*4 + 0..3 -> b128 write
      float4 o = {fmaf(-2.f, ac[rg].x, sqc), fmaf(-2.f, ac[rg].y, sqc),
                  fmaf(-2.f, ac[rg].z, sqc), fmaf(-2.f, ac[rg].w, sqc)};
      *(float4*)&scoreT[crow * SCST + rg * 16 + quad * 4] = o;
    }
    __syncthreads();   // scores ready; cs(ct) consumed

    // ---- scan phase: stage tile ct+1 -> LDS, prefetch ct+2 -> regs ----
#pragma unroll
    for (int it = 0; it < 4; ++it) {
      int chunk = tid + it * 256;
      int row = chunk >> 4, c = chunk & 15;
      int p = c ^ (row & 7);
      *(uint4*)&csHi[row * 128 + p * 8] = pH[it];
      *(uint4*)&csLo[row * 128 + p * 8] = pL[it];
    }
    if (tid < CT) sqs[tid] = psq;
    int nt = (ct + 2) & (NTILE - 1);
#pragma unroll
    for (int it = 0; it < 4; ++it) {
      int chunk = tid + it * 256;
      int row = chunk >> 4, c = chunk & 15;
      long grow = brow + (long)nt * CT + row;
      pH[it] = *(const uint4*)(hHi + grow * CC + c * 8);
      pL[it] = *(const uint4*)(hLo + grow * CC + c * 8);
    }
    if (tid < CT) psq = sqv[brow + (long)nt * CT + tid];

    // thread (q, quarter) scans candidates quarter*16..+15 of this tile
    int gbase = ct * CT + quarter * 16;
    const float* scol = &scoreT[(quarter * 16) * SCST + q];
    float thr = dk[8];
#pragma unroll
    for (int jj = 0; jj < 16; jj += 4) {
      float s0 = scol[(jj + 0) * SCST];
      float s1 = scol[(jj + 1) * SCST];
      float s2 = scol[(jj + 2) * SCST];
      float s3 = scol[(jj + 3) * SCST];
      float mn = fminf(fminf(s0, s1), fminf(s2, s3));
      if (mn < thr) {
        if (s0 < thr) { insert9(dk, ik, s0, gbase + jj + 0); thr = dk[8]; }
        if (s1 < thr) { insert9(dk, ik, s1, gbase + jj + 1); thr = dk[8]; }
        if (s2 < thr) { insert9(dk, ik, s2, gbase + jj + 2); thr = dk[8]; }
        if (s3 < thr) { insert9(dk, ik, s3, gbase + jj + 3); thr = dk[8]; }
      }
    }
    __syncthreads();   // cs(ct+1)/sqs staged; scoreT consumed
  }

  // ---- merge 4 quarter top-9s per query (lexicographic tie-break) ----
  float* mD = scoreT;                        // 3*64*9 = 1728 floats
  int*   mI = (int*)(scoreT + 1728);         // 1728 ints
  int*   fI = (int*)(scoreT + 3456);         // 576 ints (fits: 4352 total)
  if (quarter > 0) {
    int base = (quarter - 1) * 576 + q * 9;
#pragma unroll
    for (int k = 0; k < 9; ++k) { mD[base + k] = dk[k]; mI[base + k] = ik[k]; }
  }
  __syncthreads();
  if (quarter == 0) {
#pragma unroll 1
    for (int qq = 0; qq < 3; ++qq) {
      int base = qq * 576 + q * 9;
#pragma unroll 1
      for (int k = 0; k < 9; ++k)
        insert9_lex(dk, ik, mD[base + k], mI[base + k]);
    }
#pragma unroll
    for (int k = 0; k < 9; ++k) fI[q * 9 + k] = ik[k];
  }
  __syncthreads();

  // ---- aggregation: agg[q,c] = max_k h[nbr_k][c] - h[q][c] -> cat[:,128:256]
  int nb[9];
#pragma unroll
  for (int k = 0; k < 9; ++k) nb[k] = fI[q * 9 + k];
  long qrow = rowbase + q;
  const float4* cat4 = (const float4*)cat;
  float4* catw4 = (float4*)catw;
#pragma unroll 1
  for (int c4 = 0; c4 < 8; ++c4) {
    int cc = quarter * 8 + c4;
    float4 hq = cat4[qrow * 64 + cc];
    float4 mx = {-FLT_MAX, -FLT_MAX, -FLT_MAX, -FLT_MAX};
#pragma unroll
    for (int k = 0; k < 9; ++k) {
      float4 v = cat4[(brow + nb[k]) * 64 + cc];
      mx.x = fmaxf(mx.x, v.x - hq.x);
      mx.y = fmaxf(mx.y, v.y - hq.y);
      mx.z = fmaxf(mx.z, v.z - hq.z);
      mx.w = fmaxf(mx.w, v.w - hq.w);
    }
    catw4[qrow * 64 + 32 + cc] = mx;
  }
}

// ---------------------------------------------------------------------------
// BN + exact GELU (stage 2)
// ---------------------------------------------------------------------------
__global__ __launch_bounds__(256)
void bn_gelu_kernel(const float* __restrict__ X, const float* __restrict__ sum,
                    const float* __restrict__ sumsq, const float* __restrict__ g,
                    const float* __restrict__ be, float* __restrict__ out) {
  int gid = blockIdx.x * 256 + threadIdx.x;
  int row = gid >> 5;
  int c4 = (gid & 31) * 4;
  const float inv = 1.0f / (float)MROWS;
  float4 x  = *(const float4*)&X[(long)row * CC + c4];
  float4 sm = *(const float4*)&sum[c4];
  float4 sq = *(const float4*)&sumsq[c4];
  float4 gv = *(const float4*)&g[c4];
  float4 bv = *(const float4*)&be[c4];
  float xv[4] = {x.x, x.y, x.z, x.w};
  float smv[4] = {sm.x, sm.y, sm.z, sm.w};
  float sqv2[4] = {sq.x, sq.y, sq.z, sq.w};
  float ga[4] = {gv.x, gv.y, gv.z, gv.w};
  float ba[4] = {bv.x, bv.y, bv.z, bv.w};
  float o[4];
#pragma unroll
  for (int e = 0; e < 4; ++e) {
    float m = smv[e] * inv;
    float v = sqv2[e] * inv - m * m;
    float sc = ga[e] * rsqrtf(v + EPSBN);
    float h = (xv[e] - m) * sc + ba[e];
    o[e] = 0.5f * h * (1.0f + erff(h * 0.70710678118654752f));
  }
  float4 ov = {o[0], o[1], o[2], o[3]};
  *(float4*)&out[(long)row * CC + c4] = ov;
}

// ---------------------------------------------------------------------------
// BN + residual (stage 3) -> d_out
// ---------------------------------------------------------------------------
__global__ __launch_bounds__(256)
void bn_res_kernel(const float* __restrict__ X, const float* __restrict__ sum,
                   const float* __restrict__ sumsq, const float* __restrict__ g,
                   const float* __restrict__ be, const float* __restrict__ xres,
                   float* __restrict__ out) {
  int gid = blockIdx.x * 256 + threadIdx.x;
  int row = gid >> 5;
  int c4 = (gid & 31) * 4;
  const float inv = 1.0f / (float)MROWS;
  float4 x  = *(const float4*)&X[(long)row * CC + c4];
  float4 rr = *(const float4*)&xres[(long)row * CC + c4];
  float4 sm = *(const float4*)&sum[c4];
  float4 sq = *(const float4*)&sumsq[c4];
  float4 gv = *(const float4*)&g[c4];
  float4 bv = *(const float4*)&be[c4];
  float xv[4] = {x.x, x.y, x.z, x.w};
  float rv[4] = {rr.x, rr.y, rr.z, rr.w};
  float smv[4] = {sm.x, sm.y, sm.z, sm.w};
  float sqv2[4] = {sq.x, sq.y, sq.z, sq.w};
  float ga[4] = {gv.x, gv.y, gv.z, gv.w};
  float ba[4] = {bv.x, bv.y, bv.z, bv.w};
  float o[4];
#pragma unroll
  for (int e = 0; e < 4; ++e) {
    float m = smv[e] * inv;
    float v = sqv2[e] * inv - m * m;
    float sc = ga[e] * rsqrtf(v + EPSBN);
    o[e] = (xv[e] - m) * sc + ba[e] + rv[e];
  }
  float4 ov = {o[0], o[1], o[2], o[3]};
  *(float4*)&out[(long)row * CC + c4] = ov;
}

// ---------------------------------------------------------------------------
extern "C" void kernel_launch(void* const* d_in, const int* in_sizes, int n_in,
                              void* d_out, int out_size, void* d_ws, size_t ws_size,
                              hipStream_t stream) {
  const float* x   = (const float*)d_in[0];
  const float* W1  = (const float*)d_in[1];
  const float* b1  = (const float*)d_in[2];
  const float* g1  = (const float*)d_in[3];
  const float* be1 = (const float*)d_in[4];
  const float* Wg  = (const float*)d_in[5];
  const float* bg  = (const float*)d_in[6];
  const float* ggp = (const float*)d_in[7];
  const float* beg = (const float*)d_in[8];
  const float* W2  = (const float*)d_in[9];
  const float* b2  = (const float*)d_in[10];
  const float* g2  = (const float*)d_in[11];
  const float* be2 = (const float*)d_in[12];
  float* out = (float*)d_out;

  char* p = (char*)d_ws;
  auto alloc = [&](size_t bytes) {
    char* r = p;
    p += (bytes + 255) & ~(size_t)255;
    return r;
  };
  float*  bufA = (float*)alloc((size_t)MROWS * CC * 4);    // h_pre / hg_pre / out_pre
  float*  cat  = (float*)alloc((size_t)MROWS * 256 * 4);   // [h | agg]
  ushort* hHi  = (ushort*)alloc((size_t)MROWS * CC * 2);
  ushort* hLo  = (ushort*)alloc((size_t)MROWS * CC * 2);
  float*  sqv  = (float*)alloc((size_t)MROWS * 4);
  float*  hg   = (float*)alloc((size_t)MROWS * CC * 4);
  float*  stats = (float*)alloc(6 * CC * 4);
  float* sum1 = stats,       *ss1 = stats + 128;
  float* sum2 = stats + 256, *ss2 = stats + 384;
  float* sum3 = stats + 512, *ss3 = stats + 640;

  hipMemsetAsync(stats, 0, 6 * CC * 4, stream);

  // fc1 + BN -> h (fp32 in cat[:, :128]) + bf16 hi/lo split + row norms
  gemm_bias_kernel<<<MROWS / GBM, 256, 0, stream>>>(x, W1, b1, bufA, MROWS, CC);
  colstats_kernel<<<128, 256, 0, stream>>>(bufA, sum1, ss1);
  bn_split_kernel<<<MROWS / 8, 256, 0, stream>>>(bufA, sum1, ss1, g1, be1, cat, hHi, hLo, sqv);

  // KNN (split-bf16 MFMA distances, 3-pass) + top-9 + max-rel agg -> cat[:,128:]
  knn_agg_kernel<<<512, 256, 0, stream>>>(hHi, hLo, sqv, cat, cat);

  // graph MLP: cat @ Wg + BN + GELU
  gemm_bias_kernel<<<MROWS / GBM, 256, 0, stream>>>(cat, Wg, bg, bufA, MROWS, 2 * CC);
  colstats_kernel<<<128, 256, 0, stream>>>(bufA, sum2, ss2);
  bn_gelu_kernel<<<MROWS / 8, 256, 0, stream>>>(bufA, sum2, ss2, ggp, beg, hg);

  // fc2 + BN + residual
  gemm_bias_kernel<<<MROWS / GBM, 256, 0, stream>>>(hg, W2, b2, bufA, MROWS, CC);
  colstats_kernel<<<128, 256, 0, stream>>>(bufA, sum3, ss3);
  bn_res_kernel<<<MROWS / 8, 256, 0, stream>>>(bufA, sum3, ss3, g2, be2, x, out);
}

// Round 5
// 446.124 us; speedup vs baseline: 2.6934x; 1.2844x over previous
//
#include <hip/hip_runtime.h>
#include <hip/hip_bf16.h>
#include <float.h>
#include <math.h>

#define BB 8
#define NN 4096
#define CC 128
#define MROWS (BB * NN)   // 32768
#define EPSBN 1e-5f

#define QB 64             // queries per knn block
#define CT 64             // candidates per tile
#define NTILE (NN / CT)   // 64

typedef __attribute__((ext_vector_type(8))) short bf16x8;
typedef __attribute__((ext_vector_type(4))) float f32x4;

#define GLOBAL_AS __attribute__((address_space(1)))
#define LDS_AS __attribute__((address_space(3)))

__device__ __forceinline__ ushort f2bf(float f) {
  uint u = __float_as_uint(f);
  u = u + 0x7fffu + ((u >> 16) & 1u);   // RNE
  return (ushort)(u >> 16);
}
__device__ __forceinline__ float bf2f(ushort h) {
  return __uint_as_float(((uint)h) << 16);
}

// ---------------------------------------------------------------------------
// Generic fp32 GEMM: out[M,128] = A[M,K] @ W[K,128] + bias
// ---------------------------------------------------------------------------
#define GBM 64
#define GBN 128
#define GBK 32

__global__ __launch_bounds__(256)
void gemm_bias_kernel(const float* __restrict__ A, const float* __restrict__ W,
                      const float* __restrict__ bias, float* __restrict__ out,
                      int M, int K) {
  __shared__ float As[GBK][GBM + 4];
  __shared__ float Ws[GBK][GBN + 4];
  int tid = threadIdx.x;
  int m0 = blockIdx.x * GBM;
  int ty = tid >> 4, tx = tid & 15;

  float acc[4][8];
#pragma unroll
  for (int i = 0; i < 4; ++i)
#pragma unroll
    for (int j = 0; j < 8; ++j) acc[i][j] = 0.f;

  for (int k0 = 0; k0 < K; k0 += GBK) {
    {
      int row = tid >> 2, ch = tid & 3;
      const float* ap = A + (long)(m0 + row) * K + k0 + ch * 8;
      float4 a0 = *(const float4*)ap;
      float4 a1 = *(const float4*)(ap + 4);
      float av2[8] = {a0.x, a0.y, a0.z, a0.w, a1.x, a1.y, a1.z, a1.w};
#pragma unroll
      for (int e = 0; e < 8; ++e) As[ch * 8 + e][row] = av2[e];
    }
#pragma unroll
    for (int c = 0; c < 4; ++c) {
      int lin = tid + 256 * c;
      int row = lin >> 5, c4 = (lin & 31) * 4;
      *(float4*)&Ws[row][c4] = *(const float4*)&W[(long)(k0 + row) * GBN + c4];
    }
    __syncthreads();
#pragma unroll
    for (int kk = 0; kk < GBK; ++kk) {
      float4 a4 = *(const float4*)&As[kk][ty * 4];
      float4 b0 = *(const float4*)&Ws[kk][tx * 8];
      float4 b1 = *(const float4*)&Ws[kk][tx * 8 + 4];
      float av[4] = {a4.x, a4.y, a4.z, a4.w};
      float bv[8] = {b0.x, b0.y, b0.z, b0.w, b1.x, b1.y, b1.z, b1.w};
#pragma unroll
      for (int i = 0; i < 4; ++i)
#pragma unroll
        for (int j = 0; j < 8; ++j)
          acc[i][j] = fmaf(av[i], bv[j], acc[i][j]);
    }
    __syncthreads();
  }
  float4 bi0 = *(const float4*)&bias[tx * 8];
  float4 bi1 = *(const float4*)&bias[tx * 8 + 4];
#pragma unroll
  for (int i = 0; i < 4; ++i) {
    long r = (long)(m0 + ty * 4 + i);
    float4 o0 = {acc[i][0] + bi0.x, acc[i][1] + bi0.y, acc[i][2] + bi0.z, acc[i][3] + bi0.w};
    float4 o1 = {acc[i][4] + bi1.x, acc[i][5] + bi1.y, acc[i][6] + bi1.z, acc[i][7] + bi1.w};
    *(float4*)&out[r * GBN + tx * 8] = o0;
    *(float4*)&out[r * GBN + tx * 8 + 4] = o1;
  }
}

// ---------------------------------------------------------------------------
// Column stats: sum/sumsq per channel over 32768 rows (atomics into zeroed ws)
// ---------------------------------------------------------------------------
__global__ __launch_bounds__(256)
void colstats_kernel(const float* __restrict__ X, float* __restrict__ sum,
                     float* __restrict__ sumsq) {
  __shared__ float s1[256], s2[256];
  int tid = threadIdx.x;
  int c = tid & 127, rg = tid >> 7;
  int r0 = blockIdx.x * 256;
  float s = 0.f, ss = 0.f;
  for (int i = 0; i < 128; ++i) {
    float v = X[(long)(r0 + rg + i * 2) * CC + c];
    s += v; ss += v * v;
  }
  s1[tid] = s; s2[tid] = ss;
  __syncthreads();
  if (rg == 0) {
    s += s1[tid + 128]; ss += s2[tid + 128];
    atomicAdd(&sum[c], s);
    atomicAdd(&sumsq[c], ss);
  }
}

// ---------------------------------------------------------------------------
// BN apply (stage 1) + h into cat[:, :128] + bf16 hi/lo split + row sq-norms
// ---------------------------------------------------------------------------
__global__ __launch_bounds__(256)
void bn_split_kernel(const float* __restrict__ X, const float* __restrict__ sum,
                     const float* __restrict__ sumsq, const float* __restrict__ g,
                     const float* __restrict__ be, float* __restrict__ cat,
                     ushort* __restrict__ hHi, ushort* __restrict__ hLo,
                     float* __restrict__ sqv) {
  int gid = blockIdx.x * 256 + threadIdx.x;   // quad id
  int row = gid >> 5;
  int c4 = (gid & 31) * 4;
  const float inv = 1.0f / (float)MROWS;
  float4 x  = *(const float4*)&X[(long)row * CC + c4];
  float4 sm = *(const float4*)&sum[c4];
  float4 sq = *(const float4*)&sumsq[c4];
  float4 gv = *(const float4*)&g[c4];
  float4 bv = *(const float4*)&be[c4];
  float xv[4] = {x.x, x.y, x.z, x.w};
  float smv[4] = {sm.x, sm.y, sm.z, sm.w};
  float sqv2[4] = {sq.x, sq.y, sq.z, sq.w};
  float ga[4] = {gv.x, gv.y, gv.z, gv.w};
  float ba[4] = {bv.x, bv.y, bv.z, bv.w};
  float h[4];
  ushort hi[4], lo[4];
#pragma unroll
  for (int e = 0; e < 4; ++e) {
    float m = smv[e] * inv;
    float v = sqv2[e] * inv - m * m;
    float sc = ga[e] * rsqrtf(v + EPSBN);
    h[e] = (xv[e] - m) * sc + ba[e];
    hi[e] = f2bf(h[e]);
    lo[e] = f2bf(h[e] - bf2f(hi[e]));
  }
  float4 hv = {h[0], h[1], h[2], h[3]};
  *(float4*)&cat[(long)row * 256 + c4] = hv;
  ushort4 h4 = {hi[0], hi[1], hi[2], hi[3]};
  ushort4 l4 = {lo[0], lo[1], lo[2], lo[3]};
  *(ushort4*)&hHi[(long)row * CC + c4] = h4;
  *(ushort4*)&hLo[(long)row * CC + c4] = l4;
  // fused row squared-norm: 32 threads per row (within one 32-lane half)
  float s = h[0] * h[0] + h[1] * h[1] + h[2] * h[2] + h[3] * h[3];
#pragma unroll
  for (int off = 16; off >= 1; off >>= 1) s += __shfl_xor(s, off, 64);
  if ((threadIdx.x & 31) == 0) sqv[row] = s;
}

// ---------------------------------------------------------------------------
// top-9 sorted insert (fully unrolled predicated network, stays in registers)
// ---------------------------------------------------------------------------
__device__ __forceinline__ void insert9(float (&dk)[9], int (&ik)[9], float s, int idx) {
  bool sh[9];
#pragma unroll
  for (int k = 0; k < 9; ++k) sh[k] = s < dk[k];
#pragma unroll
  for (int k = 8; k >= 1; --k) {
    if (sh[k]) {
      bool up = sh[k - 1];
      dk[k] = up ? dk[k - 1] : s;
      ik[k] = up ? ik[k - 1] : idx;
    }
  }
  if (sh[0]) { dk[0] = s; ik[0] = idx; }
}

__device__ __forceinline__ void insert9_lex(float (&dk)[9], int (&ik)[9], float pd, int pi) {
  bool ins = (pd < dk[8]) || (pd == dk[8] && pi < ik[8]);
  if (ins) {
    bool sh[9];
#pragma unroll
    for (int t = 0; t < 9; ++t)
      sh[t] = (pd < dk[t]) || (pd == dk[t] && pi < ik[t]);
#pragma unroll
    for (int t = 8; t >= 1; --t) {
      if (sh[t]) {
        bool up = sh[t - 1];
        dk[t] = up ? dk[t - 1] : pd;
        ik[t] = up ? ik[t - 1] : pi;
      }
    }
    if (sh[0]) { dk[0] = pd; ik[0] = pi; }
  }
}

// ---------------------------------------------------------------------------
// Fused: pairwise dist (split-bf16, 3 MFMA passes) + top-9 + max-relative agg
// Block = 64 queries (512 blocks, blockIdx&7 = batch for XCD-L2 locality).
// Wave w owns candidates w*16..w*16+15; all 64 query fragments persistent in
// registers (amdgpu_waves_per_eu(2,2) pins the VGPR budget at 256 so the
// allocator cannot spill them chasing occupancy — the R2/R3/R4 failure).
// Candidate staging via global_load_lds DMA (zero VGPR): the global source is
// permuted per lane so the forced lane-contiguous LDS layout equals the
// XOR-swizzled conflict-free layout: chunk(r,d) lives at s = r*16 + (d^(r&7)).
// ---------------------------------------------------------------------------
#define SCST 68   // scoreT stride (floats)

__global__ __attribute__((amdgpu_flat_work_group_size(256, 256), amdgpu_waves_per_eu(2, 2)))
void knn_agg_kernel(const ushort* __restrict__ hHi, const ushort* __restrict__ hLo,
                    const float* __restrict__ sqv, const float* __restrict__ cat,
                    float* __restrict__ catw) {
  __shared__ ushort csHi[CT * 128];       // 16 KB, swizzled chunk order
  __shared__ ushort csLo[CT * 128];       // 16 KB
  __shared__ float  scoreT[CT * SCST];    // [cand][query], 17.4 KB

  int tid = threadIdx.x;
  int wave = tid >> 6, lane = tid & 63;
  int l15 = lane & 15, quad = lane >> 4;
  int b = blockIdx.x & 7, qt = blockIdx.x >> 3;
  long brow = (long)b * NN;
  long rowbase = brow + (long)qt * QB;

  // persistent A-fragments: all 64 queries, hi+lo (128 VGPRs)
  bf16x8 aHi[4][4], aLo[4][4];
#pragma unroll
  for (int rg = 0; rg < 4; ++rg) {
    long gq = rowbase + rg * 16 + l15;
    const ushort* ph = hHi + gq * CC + quad * 8;
    const ushort* pl = hLo + gq * CC + quad * 8;
#pragma unroll
    for (int ks = 0; ks < 4; ++ks) {
      aHi[rg][ks] = *(const bf16x8*)(ph + ks * 32);
      aLo[rg][ks] = *(const bf16x8*)(pl + ks * 32);
    }
  }

  float dk[9]; int ik[9];
#pragma unroll
  for (int k = 0; k < 9; ++k) { dk[k] = FLT_MAX; ik[k] = 0x7FFFFFFF; }
  int q = tid & 63, quarter = tid >> 6;

  // ---- prologue: DMA tile 0 into LDS ----
  {
    long gr = brow;
#pragma unroll
    for (int it = 0; it < 4; ++it) {
      int s0 = (wave * 4 + it) * 64;
      int s = s0 + lane;
      int r = s >> 4, dp = s & 15;
      int d = dp ^ (r & 7);
      const ushort* gH = hHi + (gr + r) * CC + d * 8;
      const ushort* gL = hLo + (gr + r) * CC + d * 8;
      __builtin_amdgcn_global_load_lds((const GLOBAL_AS void*)gH,
                                       (LDS_AS void*)&csHi[s0 * 8], 16, 0, 0);
      __builtin_amdgcn_global_load_lds((const GLOBAL_AS void*)gL,
                                       (LDS_AS void*)&csLo[s0 * 8], 16, 0, 0);
    }
  }
  __syncthreads();   // vmcnt(0) drain -> tile 0 resident

#pragma unroll 1
  for (int ct = 0; ct < NTILE; ++ct) {
    // ---- MFMA: this wave's 16 candidates x all 64 queries ----
    int crow = wave * 16 + l15;
    float sqc = sqv[brow + (long)ct * CT + crow];   // L2 hit, hidden under MFMA
    f32x4 ac[4];
#pragma unroll
    for (int rg = 0; rg < 4; ++rg) { ac[rg].x = 0.f; ac[rg].y = 0.f; ac[rg].z = 0.f; ac[rg].w = 0.f; }
#pragma unroll
    for (int ks = 0; ks < 4; ++ks) {
      int sb = crow * 16 + ((ks * 4 + quad) ^ (crow & 7));
      bf16x8 bHi = *(const bf16x8*)&csHi[sb * 8];
      bf16x8 bLo = *(const bf16x8*)&csLo[sb * 8];
#pragma unroll
      for (int rg = 0; rg < 4; ++rg) {
        ac[rg] = __builtin_amdgcn_mfma_f32_16x16x32_bf16(aHi[rg][ks], bHi, ac[rg], 0, 0, 0);
        ac[rg] = __builtin_amdgcn_mfma_f32_16x16x32_bf16(aHi[rg][ks], bLo, ac[rg], 0, 0, 0);
        ac[rg] = __builtin_amdgcn_mfma_f32_16x16x32_bf16(aLo[rg][ks], bHi, ac[rg], 0, 0, 0);
      }
    }
#pragma unroll
    for (int rg = 0; rg < 4; ++rg) {
      // lane holds cand crow, queries rg*16 + quad*4 + 0..3 -> b128 write
      float4 o = {fmaf(-2.f, ac[rg].x, sqc), fmaf(-2.f, ac[rg].y, sqc),
                  fmaf(-2.f, ac[rg].z, sqc), fmaf(-2.f, ac[rg].w, sqc)};
      *(float4*)&scoreT[crow * SCST + rg * 16 + quad * 4] = o;
    }
    __syncthreads();   // scores ready; cs(ct) fully consumed

    // ---- issue DMA for tile ct+1 (in flight during scan) ----
    {
      int nt = (ct + 1) & (NTILE - 1);
      long gr = brow + (long)nt * CT;
#pragma unroll
      for (int it = 0; it < 4; ++it) {
        int s0 = (wave * 4 + it) * 64;
        int s = s0 + lane;
        int r = s >> 4, dp = s & 15;
        int d = dp ^ (r & 7);
        const ushort* gH = hHi + (gr + r) * CC + d * 8;
        const ushort* gL = hLo + (gr + r) * CC + d * 8;
        __builtin_amdgcn_global_load_lds((const GLOBAL_AS void*)gH,
                                         (LDS_AS void*)&csHi[s0 * 8], 16, 0, 0);
        __builtin_amdgcn_global_load_lds((const GLOBAL_AS void*)gL,
                                         (LDS_AS void*)&csLo[s0 * 8], 16, 0, 0);
      }
    }

    // ---- scan: thread (q, quarter) scans candidates quarter*16..+15 ----
    int gbase = ct * CT + quarter * 16;
    const float* scol = &scoreT[(quarter * 16) * SCST + q];
    float thr = dk[8];
#pragma unroll
    for (int jj = 0; jj < 16; jj += 4) {
      float s0 = scol[(jj + 0) * SCST];
      float s1 = scol[(jj + 1) * SCST];
      float s2 = scol[(jj + 2) * SCST];
      float s3 = scol[(jj + 3) * SCST];
      float mn = fminf(fminf(s0, s1), fminf(s2, s3));
      if (mn < thr) {
        if (s0 < thr) { insert9(dk, ik, s0, gbase + jj + 0); thr = dk[8]; }
        if (s1 < thr) { insert9(dk, ik, s1, gbase + jj + 1); thr = dk[8]; }
        if (s2 < thr) { insert9(dk, ik, s2, gbase + jj + 2); thr = dk[8]; }
        if (s3 < thr) { insert9(dk, ik, s3, gbase + jj + 3); thr = dk[8]; }
      }
    }
    __syncthreads();   // vmcnt(0) drain -> cs(ct+1) resident; scoreT consumed
  }

  // ---- merge 4 quarter top-9s per query (lexicographic tie-break) ----
  float* mD = scoreT;                        // 3*64*9 = 1728 floats
  int*   mI = (int*)(scoreT + 1728);         // 1728 ints
  int*   fI = (int*)(scoreT + 3456);         // 576 ints (fits: 4352 total)
  if (quarter > 0) {
    int base = (quarter - 1) * 576 + q * 9;
#pragma unroll
    for (int k = 0; k < 9; ++k) { mD[base + k] = dk[k]; mI[base + k] = ik[k]; }
  }
  __syncthreads();
  if (quarter == 0) {
#pragma unroll 1
    for (int qq = 0; qq < 3; ++qq) {
      int base = qq * 576 + q * 9;
#pragma unroll 1
      for (int k = 0; k < 9; ++k)
        insert9_lex(dk, ik, mD[base + k], mI[base + k]);
    }
#pragma unroll
    for (int k = 0; k < 9; ++k) fI[q * 9 + k] = ik[k];
  }
  __syncthreads();

  // ---- aggregation: agg[q,c] = max_k h[nbr_k][c] - h[q][c] -> cat[:,128:256]
  int nb[9];
#pragma unroll
  for (int k = 0; k < 9; ++k) nb[k] = fI[q * 9 + k];
  long qrow = rowbase + q;
  const float4* cat4 = (const float4*)cat;
  float4* catw4 = (float4*)catw;
#pragma unroll 1
  for (int c4 = 0; c4 < 8; ++c4) {
    int cc = quarter * 8 + c4;
    float4 hq = cat4[qrow * 64 + cc];
    float4 mx = {-FLT_MAX, -FLT_MAX, -FLT_MAX, -FLT_MAX};
#pragma unroll
    for (int k = 0; k < 9; ++k) {
      float4 v = cat4[(brow + nb[k]) * 64 + cc];
      mx.x = fmaxf(mx.x, v.x - hq.x);
      mx.y = fmaxf(mx.y, v.y - hq.y);
      mx.z = fmaxf(mx.z, v.z - hq.z);
      mx.w = fmaxf(mx.w, v.w - hq.w);
    }
    catw4[qrow * 64 + 32 + cc] = mx;
  }
}

// ---------------------------------------------------------------------------
// BN + exact GELU (stage 2)
// ---------------------------------------------------------------------------
__global__ __launch_bounds__(256)
void bn_gelu_kernel(const float* __restrict__ X, const float* __restrict__ sum,
                    const float* __restrict__ sumsq, const float* __restrict__ g,
                    const float* __restrict__ be, float* __restrict__ out) {
  int gid = blockIdx.x * 256 + threadIdx.x;
  int row = gid >> 5;
  int c4 = (gid & 31) * 4;
  const float inv = 1.0f / (float)MROWS;
  float4 x  = *(const float4*)&X[(long)row * CC + c4];
  float4 sm = *(const float4*)&sum[c4];
  float4 sq = *(const float4*)&sumsq[c4];
  float4 gv = *(const float4*)&g[c4];
  float4 bv = *(const float4*)&be[c4];
  float xv[4] = {x.x, x.y, x.z, x.w};
  float smv[4] = {sm.x, sm.y, sm.z, sm.w};
  float sqv2[4] = {sq.x, sq.y, sq.z, sq.w};
  float ga[4] = {gv.x, gv.y, gv.z, gv.w};
  float ba[4] = {bv.x, bv.y, bv.z, bv.w};
  float o[4];
#pragma unroll
  for (int e = 0; e < 4; ++e) {
    float m = smv[e] * inv;
    float v = sqv2[e] * inv - m * m;
    float sc = ga[e] * rsqrtf(v + EPSBN);
    float h = (xv[e] - m) * sc + ba[e];
    o[e] = 0.5f * h * (1.0f + erff(h * 0.70710678118654752f));
  }
  float4 ov = {o[0], o[1], o[2], o[3]};
  *(float4*)&out[(long)row * CC + c4] = ov;
}

// ---------------------------------------------------------------------------
// BN + residual (stage 3) -> d_out
// ---------------------------------------------------------------------------
__global__ __launch_bounds__(256)
void bn_res_kernel(const float* __restrict__ X, const float* __restrict__ sum,
                   const float* __restrict__ sumsq, const float* __restrict__ g,
                   const float* __restrict__ be, const float* __restrict__ xres,
                   float* __restrict__ out) {
  int gid = blockIdx.x * 256 + threadIdx.x;
  int row = gid >> 5;
  int c4 = (gid & 31) * 4;
  const float inv = 1.0f / (float)MROWS;
  float4 x  = *(const float4*)&X[(long)row * CC + c4];
  float4 rr = *(const float4*)&xres[(long)row * CC + c4];
  float4 sm = *(const float4*)&sum[c4];
  float4 sq = *(const float4*)&sumsq[c4];
  float4 gv = *(const float4*)&g[c4];
  float4 bv = *(const float4*)&be[c4];
  float xv[4] = {x.x, x.y, x.z, x.w};
  float rv[4] = {rr.x, rr.y, rr.z, rr.w};
  float smv[4] = {sm.x, sm.y, sm.z, sm.w};
  float sqv2[4] = {sq.x, sq.y, sq.z, sq.w};
  float ga[4] = {gv.x, gv.y, gv.z, gv.w};
  float ba[4] = {bv.x, bv.y, bv.z, bv.w};
  float o[4];
#pragma unroll
  for (int e = 0; e < 4; ++e) {
    float m = smv[e] * inv;
    float v = sqv2[e] * inv - m * m;
    float sc = ga[e] * rsqrtf(v + EPSBN);
    o[e] = (xv[e] - m) * sc + ba[e] + rv[e];
  }
  float4 ov = {o[0], o[1], o[2], o[3]};
  *(float4*)&out[(long)row * CC + c4] = ov;
}

// ---------------------------------------------------------------------------
extern "C" void kernel_launch(void* const* d_in, const int* in_sizes, int n_in,
                              void* d_out, int out_size, void* d_ws, size_t ws_size,
                              hipStream_t stream) {
  const float* x   = (const float*)d_in[0];
  const float* W1  = (const float*)d_in[1];
  const float* b1  = (const float*)d_in[2];
  const float* g1  = (const float*)d_in[3];
  const float* be1 = (const float*)d_in[4];
  const float* Wg  = (const float*)d_in[5];
  const float* bg  = (const float*)d_in[6];
  const float* ggp = (const float*)d_in[7];
  const float* beg = (const float*)d_in[8];
  const float* W2  = (const float*)d_in[9];
  const float* b2  = (const float*)d_in[10];
  const float* g2  = (const float*)d_in[11];
  const float* be2 = (const float*)d_in[12];
  float* out = (float*)d_out;

  char* p = (char*)d_ws;
  auto alloc = [&](size_t bytes) {
    char* r = p;
    p += (bytes + 255) & ~(size_t)255;
    return r;
  };
  float*  bufA = (float*)alloc((size_t)MROWS * CC * 4);    // h_pre / hg_pre / out_pre
  float*  cat  = (float*)alloc((size_t)MROWS * 256 * 4);   // [h | agg]
  ushort* hHi  = (ushort*)alloc((size_t)MROWS * CC * 2);
  ushort* hLo  = (ushort*)alloc((size_t)MROWS * CC * 2);
  float*  sqv  = (float*)alloc((size_t)MROWS * 4);
  float*  hg   = (float*)alloc((size_t)MROWS * CC * 4);
  float*  stats = (float*)alloc(6 * CC * 4);
  float* sum1 = stats,       *ss1 = stats + 128;
  float* sum2 = stats + 256, *ss2 = stats + 384;
  float* sum3 = stats + 512, *ss3 = stats + 640;

  hipMemsetAsync(stats, 0, 6 * CC * 4, stream);

  // fc1 + BN -> h (fp32 in cat[:, :128]) + bf16 hi/lo split + row norms
  gemm_bias_kernel<<<MROWS / GBM, 256, 0, stream>>>(x, W1, b1, bufA, MROWS, CC);
  colstats_kernel<<<128, 256, 0, stream>>>(bufA, sum1, ss1);
  bn_split_kernel<<<MROWS / 8, 256, 0, stream>>>(bufA, sum1, ss1, g1, be1, cat, hHi, hLo, sqv);

  // KNN (split-bf16 MFMA distances, 3-pass) + top-9 + max-rel agg -> cat[:,128:]
  knn_agg_kernel<<<512, 256, 0, stream>>>(hHi, hLo, sqv, cat, cat);

  // graph MLP: cat @ Wg + BN + GELU
  gemm_bias_kernel<<<MROWS / GBM, 256, 0, stream>>>(cat, Wg, bg, bufA, MROWS, 2 * CC);
  colstats_kernel<<<128, 256, 0, stream>>>(bufA, sum2, ss2);
  bn_gelu_kernel<<<MROWS / 8, 256, 0, stream>>>(bufA, sum2, ss2, ggp, beg, hg);

  // fc2 + BN + residual
  gemm_bias_kernel<<<MROWS / GBM, 256, 0, stream>>>(hg, W2, b2, bufA, MROWS, CC);
  colstats_kernel<<<128, 256, 0, stream>>>(bufA, sum3, ss3);
  bn_res_kernel<<<MROWS / 8, 256, 0, stream>>>(bufA, sum3, ss3, g2, be2, x, out);
}